// Round 4
// baseline (894.596 us; speedup 1.0000x reference)
//
#include <hip/hip_runtime.h>
#include <hip/hip_bf16.h>

// dims: Bk=16, n=256, E=768, G=128, Cout_g=256, Cin_g=192, B=4, K=4, L=16, H=16, D=64
// out = [pooled 16*768][batch 131072*Tmax][valid 4*Tmax]
// ws (int32): [0..15] len per bseq, [16..31] cum, [32..35] total per b

typedef float f32x4 __attribute__((ext_vector_type(4)));
typedef __bf16 bf16x8 __attribute__((ext_vector_type(8)));
typedef unsigned short u16x4 __attribute__((ext_vector_type(4)));
typedef unsigned short u16x8 __attribute__((ext_vector_type(8)));

__device__ __forceinline__ unsigned short f2bf(float f) {
    union { float f; unsigned u; } v; v.f = f;
    unsigned r = v.u + 0x7FFFu + ((v.u >> 16) & 1u);
    return (unsigned short)(r >> 16);
}

__device__ __forceinline__ bf16x8 ldfrag(const unsigned short* p) {
    u16x8 r = *(const u16x8*)p;
    return __builtin_bit_cast(bf16x8, r);
}

// lens + prefix sums + valid flags
__global__ void cums_kernel(const int* __restrict__ mask, int* __restrict__ ws,
                            float* __restrict__ valid_out, int Tmax) {
    int tid = threadIdx.x;
    int w = tid >> 6, lane = tid & 63;
    int m = mask[w * 256 + lane] + mask[w * 256 + lane + 64] +
            mask[w * 256 + lane + 128] + mask[w * 256 + lane + 192];
#pragma unroll
    for (int off = 32; off > 0; off >>= 1) m += __shfl_down(m, off);
    if (lane == 0) ws[w] = m;
    __syncthreads();
    if (tid == 0) {
        for (int b = 0; b < 4; ++b) {
            int c = 0;
            for (int j = 0; j < 4; ++j) { ws[16 + b * 4 + j] = c; c += ws[b * 4 + j]; }
            ws[32 + b] = c;
        }
    }
    __syncthreads();
    for (int i = tid; i < 4 * Tmax; i += 1024) {
        int b = i / Tmax;
        int T = i - b * Tmax;
        valid_out[i] = (T < ws[32 + b]) ? 1.0f : 0.0f;
    }
}

// pooled: block = (bs, e-chunk of 64), 256 threads = 4 t-groups x 64 e
__global__ void pooled_kernel(const float* __restrict__ lh, const int* __restrict__ mask,
                              const int* __restrict__ ws, float* __restrict__ pooled) {
    int bs = blockIdx.x / 12;
    int ec = blockIdx.x - bs * 12;
    int tid = threadIdx.x;
    int tg = tid >> 6, lane = tid & 63;
    int e = ec * 64 + lane;
    float s = 0.f;
    for (int t = tg; t < 256; t += 4) {
        float mf = (float)mask[bs * 256 + t];
        s += lh[(size_t)(bs * 256 + t) * 768 + e] * mf;
    }
    __shared__ float red[4][64];
    red[tg][lane] = s;
    __syncthreads();
    if (tg == 0) {
        float tot = red[0][lane] + red[1][lane] + red[2][lane] + red[3][lane];
        pooled[bs * 768 + e] = tot / (float)ws[bs];
    }
}

// zero batch[l,s,b,h,T,d] for T in [total[b], Tmax)
__global__ void zerotail_kernel(float* __restrict__ batch, const int* __restrict__ ws,
                                int Tmax, int tailN) {
    int i = blockIdx.x * 256 + threadIdx.x;
    int per = tailN * 8192;
    if (i >= 4 * per) return;
    int b = i / per;
    int r = i - b * per;
    int toff = r >> 13;
    int q = r & 8191;
    int T = Tmax - 1 - toff;
    if (T < ws[32 + b]) return;
    int l = q >> 9, s = (q >> 8) & 1, h = (q >> 4) & 15, dq = q & 15;
    size_t off = ((((size_t)((l * 2 + s) * 4 + b) * 16 + h) * Tmax + T) * 64) + (dq << 2);
    f32x4 z = {0.f, 0.f, 0.f, 0.f};
    *(f32x4*)(batch + off) = z;
}

// Beta-pair fused GEMM. block = (gp, bs, nt): M=512 (2 groups x 256 o), N=128 t, K=192.
// 512 threads = 8 waves, wave tile 512x16 (full M, 16 t), acc[32] f32x4.
// Lane owns d = bp*32 + 0..31 (128B line) for one t and 4 h values.
// Grid decode co-locates all 32 (bs,nt) blocks of a pair on one XCD.
__global__ __launch_bounds__(512, 4) void gemm_kernel(
    const float* __restrict__ lh, const float* __restrict__ wgt,
    const float* __restrict__ bias, const int* __restrict__ ws,
    float* __restrict__ out, int Tmax) {
    __shared__ __align__(16) unsigned short As[512][40];    // [bl*256+o][k], row 80B (16B-aligned)
    __shared__ __align__(16) unsigned short Bs[2][128][40]; // [bl][t][k]
    __shared__ float biasS[512];

    int x = blockIdx.x;
    int xcd = x & 7;
    int kf = x >> 3;
    int gp_hi = kf & 7;
    int j = kf >> 3;               // 0..31
    int gp = gp_hi * 8 + xcd;      // 0..63, pair id; gp%8 == xcd
    int bs = j >> 1;
    int nt = j & 1;

    int len = ws[bs];
    int tbase = nt << 7;

    int tid = threadIdx.x;
    biasS[tid] = bias[(gp << 9) + tid];

    if (tbase >= len) return;

    int bp = gp & 1;               // d-half: d = bp*32 + im
    int ls = gp >> 1;              // l*2+s

    const float* Agp = wgt + (size_t)gp * 98304;                       // 512 x 192 row-major
    const float* Bgp = lh + (size_t)bs * 196608 + (size_t)tbase * 768 + bp * 384;

    int lane = tid & 63;
    int wn = tid >> 6;             // wave -> t chunk
    int p = lane & 15;
    int q = lane >> 4;
    int q8 = q << 3;

    f32x4 acc[32] = {};

    for (int kk = 0; kk < 192; kk += 32) {
        // stage A: 512 rows x 32 f32 -> bf16 (8 f32x4 per thread)
#pragma unroll
        for (int it = 0; it < 8; ++it) {
            int idx = tid + (it << 9);
            int row = idx >> 3;
            int c4 = (idx & 7) << 2;
            f32x4 av = *(const f32x4*)(Agp + row * 192 + kk + c4);
            u16x4 aw = { f2bf(av[0]), f2bf(av[1]), f2bf(av[2]), f2bf(av[3]) };
            *(u16x4*)&As[row][c4] = aw;
        }
        // stage B: 2 slices x 128 t x 32 f32 (4 f32x4 per thread)
#pragma unroll
        for (int it = 0; it < 4; ++it) {
            int idx = tid + (it << 9);
            int bl = idx >> 10;
            int rem = idx & 1023;
            int trow = rem >> 3;
            int c4 = (rem & 7) << 2;
            f32x4 bv = *(const f32x4*)(Bgp + (size_t)trow * 768 + bl * 192 + kk + c4);
            u16x4 bw = { f2bf(bv[0]), f2bf(bv[1]), f2bf(bv[2]), f2bf(bv[3]) };
            *(u16x4*)&Bs[bl][trow][c4] = bw;
        }
        __syncthreads();

#pragma unroll
        for (int bl = 0; bl < 2; ++bl) {
            bf16x8 bf = ldfrag(&Bs[bl][(wn << 4) + p][q8]);
#pragma unroll
            for (int d16 = 0; d16 < 16; ++d16) {
                int im = (bl << 4) + d16;
                bf16x8 af = ldfrag(&As[(im << 4) + p][q8]);
                acc[im] = __builtin_amdgcn_mfma_f32_16x16x32_bf16(af, bf, acc[im], 0, 0, 0);
            }
        }
        __syncthreads();
    }

    // epilogue: lane owns t = tbase + wn*16 + p, h = q*4 + r, d = bp*32 + im (im=0..31)
    int t = tbase + (wn << 4) + p;
    if (t >= len) return;

    int cum = ws[16 + bs];
    int b = bs >> 2;
    float* batch = out + 12288;

    size_t hd0 = (size_t)((ls << 2) + b) << 4;     // (ls*4+b)*16
    size_t tb = (size_t)(cum + t);
    int h0 = q << 2;

#pragma unroll
    for (int r = 0; r < 4; ++r) {
        size_t off = ((hd0 + h0 + r) * (size_t)Tmax + tb) * 64 + (bp << 5);
#pragma unroll
        for (int jj = 0; jj < 8; ++jj) {
            f32x4 v = { acc[(jj << 2) + 0][r] + biasS[(((jj << 2) + 0) << 4) + h0 + r],
                        acc[(jj << 2) + 1][r] + biasS[(((jj << 2) + 1) << 4) + h0 + r],
                        acc[(jj << 2) + 2][r] + biasS[(((jj << 2) + 2) << 4) + h0 + r],
                        acc[(jj << 2) + 3][r] + biasS[(((jj << 2) + 3) << 4) + h0 + r] };
            *(f32x4*)(batch + off + (jj << 2)) = v;
        }
    }
}

extern "C" void kernel_launch(void* const* d_in, const int* in_sizes, int n_in,
                              void* d_out, int out_size, void* d_ws, size_t ws_size,
                              hipStream_t stream) {
    const float* lh   = (const float*)d_in[0];
    const int*   mask = (const int*)d_in[1];
    const float* wgt  = (const float*)d_in[2];
    const float* bias = (const float*)d_in[3];
    float* out = (float*)d_out;
    int* ws = (int*)d_ws;

    int Tmax = (out_size - 12288) / 131076;

    cums_kernel<<<1, 1024, 0, stream>>>(mask, ws, out + 12288 + (size_t)131072 * Tmax, Tmax);
    pooled_kernel<<<16 * 12, 256, 0, stream>>>(lh, mask, ws, out);

    int tailN = Tmax - 512; if (tailN < 1) tailN = 1;
    int nz = 4 * tailN * 8192;
    zerotail_kernel<<<(nz + 255) / 256, 256, 0, stream>>>(out + 12288, ws, Tmax, tailN);

    gemm_kernel<<<2048, 512, 0, stream>>>(lh, wgt, bias, ws, out, Tmax);
}

// Round 5
// 696.208 us; speedup vs baseline: 1.2850x; 1.2850x over previous
//
#include <hip/hip_runtime.h>
#include <hip/hip_bf16.h>

// dims: Bk=16, n=256, E=768, G=128, Cout_g=256, Cin_g=192, B=4, K=4, L=16, H=16, D=64
// out = [pooled 16*768][batch 131072*Tmax][valid 4*Tmax]
// ws (int32): [0..15] len per bseq, [16..31] cum, [32..35] total per b
// decode: g = ls*4 + beta (ls=l*2+s in 0..31), d = beta*16 + (o>>4), h = o&15

typedef float f32x4 __attribute__((ext_vector_type(4)));
typedef __bf16 bf16x8 __attribute__((ext_vector_type(8)));
typedef unsigned short u16x4 __attribute__((ext_vector_type(4)));
typedef unsigned short u16x8 __attribute__((ext_vector_type(8)));

__device__ __forceinline__ unsigned short f2bf(float f) {
    union { float f; unsigned u; } v; v.f = f;
    unsigned r = v.u + 0x7FFFu + ((v.u >> 16) & 1u);
    return (unsigned short)(r >> 16);
}

__device__ __forceinline__ bf16x8 ldfrag(const unsigned short* p) {
    u16x8 r = *(const u16x8*)p;
    return __builtin_bit_cast(bf16x8, r);
}

// lens + prefix sums + valid flags
__global__ void cums_kernel(const int* __restrict__ mask, int* __restrict__ ws,
                            float* __restrict__ valid_out, int Tmax) {
    int tid = threadIdx.x;
    int w = tid >> 6, lane = tid & 63;
    int m = mask[w * 256 + lane] + mask[w * 256 + lane + 64] +
            mask[w * 256 + lane + 128] + mask[w * 256 + lane + 192];
#pragma unroll
    for (int off = 32; off > 0; off >>= 1) m += __shfl_down(m, off);
    if (lane == 0) ws[w] = m;
    __syncthreads();
    if (tid == 0) {
        for (int b = 0; b < 4; ++b) {
            int c = 0;
            for (int j = 0; j < 4; ++j) { ws[16 + b * 4 + j] = c; c += ws[b * 4 + j]; }
            ws[32 + b] = c;
        }
    }
    __syncthreads();
    for (int i = tid; i < 4 * Tmax; i += 1024) {
        int b = i / Tmax;
        int T = i - b * Tmax;
        valid_out[i] = (T < ws[32 + b]) ? 1.0f : 0.0f;
    }
}

// pooled: block = (bs, e-chunk of 64), 256 threads = 4 t-groups x 64 e
__global__ void pooled_kernel(const float* __restrict__ lh, const int* __restrict__ mask,
                              const int* __restrict__ ws, float* __restrict__ pooled) {
    int bs = blockIdx.x / 12;
    int ec = blockIdx.x - bs * 12;
    int tid = threadIdx.x;
    int tg = tid >> 6, lane = tid & 63;
    int e = ec * 64 + lane;
    float s = 0.f;
    for (int t = tg; t < 256; t += 4) {
        float mf = (float)mask[bs * 256 + t];
        s += lh[(size_t)(bs * 256 + t) * 768 + e] * mf;
    }
    __shared__ float red[4][64];
    red[tg][lane] = s;
    __syncthreads();
    if (tg == 0) {
        float tot = red[0][lane] + red[1][lane] + red[2][lane] + red[3][lane];
        pooled[bs * 768 + e] = tot / (float)ws[bs];
    }
}

// zero batch[l,s,b,h,T,d] for T in [total[b], Tmax)
__global__ void zerotail_kernel(float* __restrict__ batch, const int* __restrict__ ws,
                                int Tmax, int tailN) {
    int i = blockIdx.x * 256 + threadIdx.x;
    int per = tailN * 8192;
    if (i >= 4 * per) return;
    int b = i / per;
    int r = i - b * per;
    int toff = r >> 13;
    int q = r & 8191;
    int T = Tmax - 1 - toff;
    if (T < ws[32 + b]) return;
    int l = q >> 9, s = (q >> 8) & 1, h = (q >> 4) & 15, dq = q & 15;
    size_t off = ((((size_t)((l * 2 + s) * 4 + b) * 16 + h) * Tmax + T) * 64) + (dq << 2);
    f32x4 z = {0.f, 0.f, 0.f, 0.f};
    *(f32x4*)(batch + off) = z;
}

// All-beta fused GEMM. block = (ls, bs, ntq): computes the 4 groups g=ls*4+beta
// over a 64-t tile. 256 threads = 4 waves x 16 t. Lane owns acc[64] = full d-row
// (256B) for one t and 4 h values -> every output line written whole by one lane.
// Grid decode pins each ls to one XCD (bid%8==ls%8): per-XCD A = 786KB L2-resident.
__global__ __launch_bounds__(256, 1) void gemm_kernel(
    const float* __restrict__ lh, const float* __restrict__ wgt,
    const float* __restrict__ bias, const int* __restrict__ ws,
    float* __restrict__ out, int Tmax) {
    __shared__ __align__(16) unsigned short As[256][36];   // [o][k], row 72B: conflict-free spread
    __shared__ __align__(16) unsigned short Bs[64][36];    // [t][k]
    __shared__ float biasT[16][68];                        // [h][d], pad 4

    int x = blockIdx.x;
    int xcd = x & 7;
    int r0 = x >> 3;
    int lsq = r0 >> 6;             // 0..3  (ls phase per XCD)
    int bsnt = r0 & 63;
    int ls = (lsq << 3) + xcd;     // 0..31
    int bs = bsnt >> 2;
    int ntq = bsnt & 3;

    int len = ws[bs];
    int tid = threadIdx.x;

    // stage bias transposed to [h][d]; d = beta*16 + (o>>4)
    {
        f32x4 bv = *(const f32x4*)(bias + (ls << 10) + (tid << 2));
#pragma unroll
        for (int u = 0; u < 4; ++u) {
            int i = (tid << 2) + u;
            int beta = i >> 8, o = i & 255;
            biasT[o & 15][(beta << 4) + (o >> 4)] = bv[u];
        }
    }

    int tbase = ntq << 6;
    if (tbase >= len) return;      // block-uniform

    const float* A0 = wgt + (size_t)ls * 196608;                    // 4 x (256 x 192)
    const float* B0 = lh + (size_t)bs * 196608 + (size_t)tbase * 768;

    int lane = tid & 63;
    int wn = tid >> 6;             // 0..3, t chunk
    int p = lane & 15;
    int q = lane >> 4;
    int q8 = q << 3;

    int ar = tid >> 3;             // 0..31 (+ it*32)
    int ac4 = (tid & 7) << 2;      // 0..28

    f32x4 acc[64] = {};
    f32x4 pa[8], pb[2];

    // prologue: load round 0 (beta=0, kk=0)
#pragma unroll
    for (int it = 0; it < 8; ++it)
        pa[it] = *(const f32x4*)(A0 + (ar + (it << 5)) * 192 + ac4);
#pragma unroll
    for (int it = 0; it < 2; ++it)
        pb[it] = *(const f32x4*)(B0 + (size_t)(ar + (it << 5)) * 768 + ac4);

#pragma unroll
    for (int rr = 0; rr < 24; ++rr) {
        const int beta = rr / 6;
        // ds_write current regs (f32 -> bf16)
#pragma unroll
        for (int it = 0; it < 8; ++it) {
            u16x4 aw = { f2bf(pa[it][0]), f2bf(pa[it][1]), f2bf(pa[it][2]), f2bf(pa[it][3]) };
            *(u16x4*)&As[ar + (it << 5)][ac4] = aw;
        }
#pragma unroll
        for (int it = 0; it < 2; ++it) {
            u16x4 bw = { f2bf(pb[it][0]), f2bf(pb[it][1]), f2bf(pb[it][2]), f2bf(pb[it][3]) };
            *(u16x4*)&Bs[ar + (it << 5)][ac4] = bw;
        }
        __syncthreads();
        // issue next round's loads (latency hides under MFMA + barriers)
        if (rr < 23) {
            const int nb = (rr + 1) / 6;
            const int nk = ((rr + 1) % 6) << 5;
#pragma unroll
            for (int it = 0; it < 8; ++it)
                pa[it] = *(const f32x4*)(A0 + nb * 49152 + (ar + (it << 5)) * 192 + nk + ac4);
#pragma unroll
            for (int it = 0; it < 2; ++it)
                pb[it] = *(const f32x4*)(B0 + (size_t)(ar + (it << 5)) * 768 + nb * 192 + nk + ac4);
        }
        // MFMA: 16 dmid tiles
        bf16x8 bf = ldfrag(&Bs[(wn << 4) + p][q8]);
#pragma unroll
        for (int dmid = 0; dmid < 16; ++dmid) {
            bf16x8 af = ldfrag(&As[(dmid << 4) + p][q8]);
            acc[(beta << 4) + dmid] =
                __builtin_amdgcn_mfma_f32_16x16x32_bf16(af, bf, acc[(beta << 4) + dmid], 0, 0, 0);
        }
        __syncthreads();
    }

    // epilogue: lane owns t, h = q*4+r, full d 0..63 (acc index == d)
    int t = tbase + (wn << 4) + p;
    if (t >= len) return;

    int cum = ws[16 + bs];
    int b = bs >> 2;
    float* batch = out + 12288;
    size_t tb = (size_t)(cum + t);
    int h0 = q << 2;

#pragma unroll
    for (int r = 0; r < 4; ++r) {
        int h = h0 + r;
        float* dst = batch + (((size_t)((ls << 2) + b) * 16 + h) * (size_t)Tmax + tb) * 64;
#pragma unroll
        for (int jj = 0; jj < 16; ++jj) {
            f32x4 bb = *(const f32x4*)&biasT[h][jj << 2];
            f32x4 v = { acc[(jj << 2) + 0][r] + bb[0],
                        acc[(jj << 2) + 1][r] + bb[1],
                        acc[(jj << 2) + 2][r] + bb[2],
                        acc[(jj << 2) + 3][r] + bb[3] };
            *(f32x4*)(dst + (jj << 2)) = v;
        }
    }
}

extern "C" void kernel_launch(void* const* d_in, const int* in_sizes, int n_in,
                              void* d_out, int out_size, void* d_ws, size_t ws_size,
                              hipStream_t stream) {
    const float* lh   = (const float*)d_in[0];
    const int*   mask = (const int*)d_in[1];
    const float* wgt  = (const float*)d_in[2];
    const float* bias = (const float*)d_in[3];
    float* out = (float*)d_out;
    int* ws = (int*)d_ws;

    int Tmax = (out_size - 12288) / 131076;

    cums_kernel<<<1, 1024, 0, stream>>>(mask, ws, out + 12288 + (size_t)131072 * Tmax, Tmax);
    pooled_kernel<<<16 * 12, 256, 0, stream>>>(lh, mask, ws, out);

    int tailN = Tmax - 512; if (tailN < 1) tailN = 1;
    int nz = 4 * tailN * 8192;
    zerotail_kernel<<<(nz + 255) / 256, 256, 0, stream>>>(out + 12288, ws, Tmax, tailN);

    gemm_kernel<<<2048, 256, 0, stream>>>(lh, wgt, bias, ws, out, Tmax);
}

// Round 6
// 620.539 us; speedup vs baseline: 1.4416x; 1.1219x over previous
//
#include <hip/hip_runtime.h>
#include <hip/hip_bf16.h>

// dims: Bk=16, n=256, E=768, G=128, Cout_g=256, Cin_g=192, B=4, K=4, L=16, H=16, D=64
// out = [pooled 16*768][batch 131072*Tmax][valid 4*Tmax]
// ws (int32): [0..15] len per bseq, [16..31] cum, [32..35] total per b
// decode: g = ls*4 + beta (ls=l*2+s in 0..31), d = beta*16 + (o>>4), h = o&15

typedef float f32x4 __attribute__((ext_vector_type(4)));
typedef __bf16 bf16x8 __attribute__((ext_vector_type(8)));
typedef unsigned short u16x4 __attribute__((ext_vector_type(4)));
typedef unsigned short u16x8 __attribute__((ext_vector_type(8)));

__device__ __forceinline__ unsigned short f2bf(float f) {
    union { float f; unsigned u; } v; v.f = f;
    unsigned r = v.u + 0x7FFFu + ((v.u >> 16) & 1u);
    return (unsigned short)(r >> 16);
}

__device__ __forceinline__ bf16x8 ldfrag(const unsigned short* p) {
    u16x8 r = *(const u16x8*)p;
    return __builtin_bit_cast(bf16x8, r);
}

// lens + prefix sums + valid flags
__global__ void cums_kernel(const int* __restrict__ mask, int* __restrict__ ws,
                            float* __restrict__ valid_out, int Tmax) {
    int tid = threadIdx.x;
    int w = tid >> 6, lane = tid & 63;
    int m = mask[w * 256 + lane] + mask[w * 256 + lane + 64] +
            mask[w * 256 + lane + 128] + mask[w * 256 + lane + 192];
#pragma unroll
    for (int off = 32; off > 0; off >>= 1) m += __shfl_down(m, off);
    if (lane == 0) ws[w] = m;
    __syncthreads();
    if (tid == 0) {
        for (int b = 0; b < 4; ++b) {
            int c = 0;
            for (int j = 0; j < 4; ++j) { ws[16 + b * 4 + j] = c; c += ws[b * 4 + j]; }
            ws[32 + b] = c;
        }
    }
    __syncthreads();
    for (int i = tid; i < 4 * Tmax; i += 1024) {
        int b = i / Tmax;
        int T = i - b * Tmax;
        valid_out[i] = (T < ws[32 + b]) ? 1.0f : 0.0f;
    }
}

// pooled: block = (bs, e-chunk of 64), 256 threads = 4 t-groups x 64 e
__global__ void pooled_kernel(const float* __restrict__ lh, const int* __restrict__ mask,
                              const int* __restrict__ ws, float* __restrict__ pooled) {
    int bs = blockIdx.x / 12;
    int ec = blockIdx.x - bs * 12;
    int tid = threadIdx.x;
    int tg = tid >> 6, lane = tid & 63;
    int e = ec * 64 + lane;
    float s = 0.f;
    for (int t = tg; t < 256; t += 4) {
        float mf = (float)mask[bs * 256 + t];
        s += lh[(size_t)(bs * 256 + t) * 768 + e] * mf;
    }
    __shared__ float red[4][64];
    red[tg][lane] = s;
    __syncthreads();
    if (tg == 0) {
        float tot = red[0][lane] + red[1][lane] + red[2][lane] + red[3][lane];
        pooled[bs * 768 + e] = tot / (float)ws[bs];
    }
}

// zero batch[l,s,b,h,T,d] for T in [total[b], Tmax)
__global__ void zerotail_kernel(float* __restrict__ batch, const int* __restrict__ ws,
                                int Tmax, int tailN) {
    int i = blockIdx.x * 256 + threadIdx.x;
    int per = tailN * 8192;
    if (i >= 4 * per) return;
    int b = i / per;
    int r = i - b * per;
    int toff = r >> 13;
    int q = r & 8191;
    int T = Tmax - 1 - toff;
    if (T < ws[32 + b]) return;
    int l = q >> 9, s = (q >> 8) & 1, h = (q >> 4) & 15, dq = q & 15;
    size_t off = ((((size_t)((l * 2 + s) * 4 + b) * 16 + h) * Tmax + T) * 64) + (dq << 2);
    f32x4 z = {0.f, 0.f, 0.f, 0.f};
    *(f32x4*)(batch + off) = z;
}

// All-beta fused GEMM with LDS-transpose epilogue.
// block = (ls, bs, ntq): 1024 o' (4 beta x 256 o) x 64 t, K=192.
// 1024 threads = 16 waves = (beta 0..3) x (tq 0..3); wave: 256 o x 16 t, acc[16] f32x4.
// Epilogue: XOR-swizzled LDS transpose -> 256 threads each store one full 256B d-row.
__global__ __launch_bounds__(1024, 4) void gemm_kernel(
    const float* __restrict__ lh, const float* __restrict__ wgt,
    const float* __restrict__ bias, const int* __restrict__ ws,
    float* __restrict__ out, int Tmax) {
    __shared__ __align__(16) unsigned short As[1024][36];   // 73728 B, reused as Ltr float[256][68]
    __shared__ __align__(16) float biasT[16][68];           // [h][d]

    int x = blockIdx.x;
    int ls = x >> 6;
    int bs = (x >> 2) & 15;
    int ntq = x & 3;

    int len = ws[bs];
    int tbase = ntq << 6;
    if (tbase >= len) return;            // block-uniform

    int tid = threadIdx.x;
    int lane = tid & 63;
    int wv = tid >> 6;
    int beta = wv >> 2;
    int tq = wv & 3;
    int p = lane & 15;
    int q = lane >> 4;
    int q8 = q << 3;

    // stage bias transposed: biasT[h][beta*16+dmid]
    {
        int bb = tid >> 8, o = tid & 255;
        biasT[o & 15][(bb << 4) + (o >> 4)] = bias[(ls << 10) + tid];
    }

    const float* Awg = wgt + (size_t)ls * 196608;            // 1024 x 192 f32
    const float* Brow = lh + (size_t)bs * 196608 +
                        (size_t)(tbase + (tq << 4) + p) * 768 + beta * 192 + q8;

    f32x4 acc[16] = {};
    f32x4 pa[4];

    // prologue: prefetch first half of chunk 0's A
#pragma unroll
    for (int it = 0; it < 4; ++it) {
        int idx = tid + (it << 10);
        int row = idx >> 3;
        int c4 = (idx & 7) << 2;
        pa[it] = *(const f32x4*)(Awg + row * 192 + c4);
    }

#pragma unroll
    for (int cc = 0; cc < 6; ++cc) {
        const int kk = cc << 5;
        // issue B loads for this chunk (consumed after barrier)
        f32x4 b0 = *(const f32x4*)(Brow + kk);
        f32x4 b1 = *(const f32x4*)(Brow + kk + 4);
        // A stage: rows 0..511 from prefetch regs, rows 512..1023 direct
#pragma unroll
        for (int it = 0; it < 4; ++it) {
            int idx = tid + (it << 10);
            int row = idx >> 3;
            int c4 = (idx & 7) << 2;
            f32x4 av = pa[it];
            u16x4 aw = { f2bf(av[0]), f2bf(av[1]), f2bf(av[2]), f2bf(av[3]) };
            *(u16x4*)&As[row][c4] = aw;
        }
#pragma unroll
        for (int it = 4; it < 8; ++it) {
            int idx = tid + (it << 10);
            int row = idx >> 3;
            int c4 = (idx & 7) << 2;
            f32x4 av = *(const f32x4*)(Awg + row * 192 + kk + c4);
            u16x4 aw = { f2bf(av[0]), f2bf(av[1]), f2bf(av[2]), f2bf(av[3]) };
            *(u16x4*)&As[row][c4] = aw;
        }
        __syncthreads();
        // prefetch next chunk's first A half (in flight across the MFMA cluster)
        if (cc < 5) {
#pragma unroll
            for (int it = 0; it < 4; ++it) {
                int idx = tid + (it << 10);
                int row = idx >> 3;
                int c4 = (idx & 7) << 2;
                pa[it] = *(const f32x4*)(Awg + row * 192 + kk + 32 + c4);
            }
        }
        // B fragment
        u16x8 bw = { f2bf(b0[0]), f2bf(b0[1]), f2bf(b0[2]), f2bf(b0[3]),
                     f2bf(b1[0]), f2bf(b1[1]), f2bf(b1[2]), f2bf(b1[3]) };
        bf16x8 bf = __builtin_bit_cast(bf16x8, bw);
        // 16 MFMA over dmid tiles of this wave's beta
        const unsigned short* abase = &As[(beta << 8) + p][q8];
#pragma unroll
        for (int dmid = 0; dmid < 16; ++dmid) {
            bf16x8 af = ldfrag(abase + dmid * 16 * 36);
            acc[dmid] = __builtin_amdgcn_mfma_f32_16x16x32_bf16(af, bf, acc[dmid], 0, 0, 0);
        }
        __syncthreads();
    }

    // ---- epilogue: LDS transpose (reuse As as Ltr float[256][68]) ----
    float* Ltr = (float*)&As[0][0];
    int cum = ws[16 + bs];
    int b = bs >> 2;
    float* batch = out + 12288;

    int t_l = (tq << 4) + p;          // this lane's t within tile (write phase)
    int tp = (t_l & 7) << 3;

#pragma unroll
    for (int r = 0; r < 4; ++r) {
        // write phase: Ltr[h'=q][t_l][d ^ swz] = acc value at h=q*4+r
        float* wrow = Ltr + ((q << 6) + t_l) * 68;
#pragma unroll
        for (int dmid = 0; dmid < 16; ++dmid) {
            int d = (beta << 4) + dmid;
            wrow[d ^ tp] = acc[dmid][r];
        }
        __syncthreads();
        // read phase: 256 threads, each one full (h,t) d-row of 64 floats
        if (tid < 256) {
            int hq = tid >> 6;
            int tl = tid & 63;
            int h = (hq << 2) + r;
            int tg = tbase + tl;
            if (tg < len) {
                const float* src = Ltr + ((hq << 6) + tl) * 68;
                int sw = (tl & 7) << 3;
                float* dst = batch + (((size_t)((ls << 2) + b) * 16 + h) * (size_t)Tmax +
                                      (size_t)(cum + tg)) * 64;
#pragma unroll
                for (int jj = 0; jj < 16; ++jj) {
                    f32x4 v = *(const f32x4*)(src + (((jj << 2) ^ sw)));
                    f32x4 bb = *(const f32x4*)&biasT[h][jj << 2];
                    v += bb;
                    *(f32x4*)(dst + (jj << 2)) = v;
                }
            }
        }
        __syncthreads();
    }
}

extern "C" void kernel_launch(void* const* d_in, const int* in_sizes, int n_in,
                              void* d_out, int out_size, void* d_ws, size_t ws_size,
                              hipStream_t stream) {
    const float* lh   = (const float*)d_in[0];
    const int*   mask = (const int*)d_in[1];
    const float* wgt  = (const float*)d_in[2];
    const float* bias = (const float*)d_in[3];
    float* out = (float*)d_out;
    int* ws = (int*)d_ws;

    int Tmax = (out_size - 12288) / 131076;

    cums_kernel<<<1, 1024, 0, stream>>>(mask, ws, out + 12288 + (size_t)131072 * Tmax, Tmax);
    pooled_kernel<<<16 * 12, 256, 0, stream>>>(lh, mask, ws, out);

    int tailN = Tmax - 512; if (tailN < 1) tailN = 1;
    int nz = 4 * tailN * 8192;
    zerotail_kernel<<<(nz + 255) / 256, 256, 0, stream>>>(out + 12288, ws, Tmax, tailN);

    gemm_kernel<<<32 * 16 * 4, 1024, 0, stream>>>(lh, wgt, bias, ws, out, Tmax);
}

// Round 7
// 350.136 us; speedup vs baseline: 2.5550x; 1.7723x over previous
//
#include <hip/hip_runtime.h>
#include <hip/hip_bf16.h>

// dims: Bk=16, n=256, E=768, G=128, Cout_g=256, Cin_g=192, B=4, K=4, L=16, H=16, D=64
// out = [pooled 16*768][batch 131072*Tmax][valid 4*Tmax]
// ws (int32): [0..15] len per bseq, [16..31] cum, [32..35] total per b
// decode: g = ls*4 + beta (ls=l*2+s), d = beta*16 + (o>>4), h = o&15

typedef float f32x4 __attribute__((ext_vector_type(4)));
typedef __bf16 bf16x8 __attribute__((ext_vector_type(8)));
typedef unsigned short u16x4 __attribute__((ext_vector_type(4)));
typedef unsigned short u16x8 __attribute__((ext_vector_type(8)));

__device__ __forceinline__ unsigned short f2bf(float f) {
    union { float f; unsigned u; } v; v.f = f;
    unsigned r = v.u + 0x7FFFu + ((v.u >> 16) & 1u);
    return (unsigned short)(r >> 16);
}

__device__ __forceinline__ bf16x8 ldfrag(const unsigned short* p) {
    u16x8 r = *(const u16x8*)p;
    return __builtin_bit_cast(bf16x8, r);
}

// lens + prefix sums + valid flags
__global__ void cums_kernel(const int* __restrict__ mask, int* __restrict__ ws,
                            float* __restrict__ valid_out, int Tmax) {
    int tid = threadIdx.x;
    int w = tid >> 6, lane = tid & 63;
    int m = mask[w * 256 + lane] + mask[w * 256 + lane + 64] +
            mask[w * 256 + lane + 128] + mask[w * 256 + lane + 192];
#pragma unroll
    for (int off = 32; off > 0; off >>= 1) m += __shfl_down(m, off);
    if (lane == 0) ws[w] = m;
    __syncthreads();
    if (tid == 0) {
        for (int b = 0; b < 4; ++b) {
            int c = 0;
            for (int j = 0; j < 4; ++j) { ws[16 + b * 4 + j] = c; c += ws[b * 4 + j]; }
            ws[32 + b] = c;
        }
    }
    __syncthreads();
    for (int i = tid; i < 4 * Tmax; i += 1024) {
        int b = i / Tmax;
        int T = i - b * Tmax;
        valid_out[i] = (T < ws[32 + b]) ? 1.0f : 0.0f;
    }
}

// pooled: block = (bs, e-chunk of 64), 256 threads = 4 t-groups x 64 e
__global__ void pooled_kernel(const float* __restrict__ lh, const int* __restrict__ mask,
                              const int* __restrict__ ws, float* __restrict__ pooled) {
    int bs = blockIdx.x / 12;
    int ec = blockIdx.x - bs * 12;
    int tid = threadIdx.x;
    int tg = tid >> 6, lane = tid & 63;
    int e = ec * 64 + lane;
    float s = 0.f;
    for (int t = tg; t < 256; t += 4) {
        float mf = (float)mask[bs * 256 + t];
        s += lh[(size_t)(bs * 256 + t) * 768 + e] * mf;
    }
    __shared__ float red[4][64];
    red[tg][lane] = s;
    __syncthreads();
    if (tg == 0) {
        float tot = red[0][lane] + red[1][lane] + red[2][lane] + red[3][lane];
        pooled[bs * 768 + e] = tot / (float)ws[bs];
    }
}

// zero batch[l,s,b,h,T,d] for T in [total[b], Tmax)
__global__ void zerotail_kernel(float* __restrict__ batch, const int* __restrict__ ws,
                                int Tmax, int tailN) {
    int i = blockIdx.x * 256 + threadIdx.x;
    int per = tailN * 8192;
    if (i >= 4 * per) return;
    int b = i / per;
    int r = i - b * per;
    int toff = r >> 13;
    int q = r & 8191;
    int T = Tmax - 1 - toff;
    if (T < ws[32 + b]) return;
    int l = q >> 9, s = (q >> 8) & 1, h = (q >> 4) & 15, dq = q & 15;
    size_t off = ((((size_t)((l * 2 + s) * 4 + b) * 16 + h) * Tmax + T) * 64) + (dq << 2);
    f32x4 z = {0.f, 0.f, 0.f, 0.f};
    *(f32x4*)(batch + off) = z;
}

// R2 gemm geometry, quad-coscheduled grid.
// bid = xcd + 8*(beta + 4*quad); quad Q = (bid>>5)*8 + (bid&7) -> (ls, bs, nthalf).
// The 4 beta-siblings of one (ls,bs,nthalf) land on the SAME XCD within 24 bids,
// so their 32B quarter-line writes merge in that XCD's L2 -> ~1.0x write amp.
// Block: M=256 (o), N=128 (t), K=192. 512 threads = 8 waves (2 wm x 4 wn),
// wave tile 128x32, fragments acc[8][2].
__global__ __launch_bounds__(512) void gemm_kernel(
    const float* __restrict__ lh, const float* __restrict__ wgt,
    const float* __restrict__ bias, const int* __restrict__ ws,
    float* __restrict__ out, int Tmax) {
    __shared__ __align__(16) unsigned short As[256][72];   // [o][k], pad 8
    __shared__ __align__(16) unsigned short Bs[128][72];   // [t][k], pad 8

    int x = blockIdx.x;
    int beta = (x >> 3) & 3;
    int Q = ((x >> 5) << 3) | (x & 7);   // 0..1023
    int ls = Q >> 5;                     // 0..31
    int bs = (Q >> 1) & 15;
    int nthalf = Q & 1;
    int g = (ls << 2) + beta;

    int len = ws[bs];
    int tbase = nthalf << 7;
    if (tbase >= len) return;

    const float* Ag = wgt + (size_t)g * 49152;
    const float* Bg = lh + (size_t)bs * 196608 + (size_t)tbase * 768 + beta * 192;

    int tid = threadIdx.x;
    int lane = tid & 63;
    int wave = tid >> 6;
    int wm = wave >> 2, wn = wave & 3;

    f32x4 acc[8][2] = {};

    for (int kk = 0; kk < 192; kk += 64) {
#pragma unroll
        for (int it = 0; it < 8; ++it) {
            int idx = tid + (it << 9);           // 0..4095
            int row = idx >> 4;
            int c4 = (idx & 15) << 2;
            f32x4 av = *(const f32x4*)(Ag + row * 192 + kk + c4);
            u16x4 aw = { f2bf(av[0]), f2bf(av[1]), f2bf(av[2]), f2bf(av[3]) };
            *(u16x4*)&As[row][c4] = aw;
        }
#pragma unroll
        for (int it = 0; it < 4; ++it) {
            int idx = tid + (it << 9);           // 0..2047
            int row = idx >> 4;
            int c4 = (idx & 15) << 2;
            f32x4 bv = *(const f32x4*)(Bg + row * 768 + kk + c4);
            u16x4 bw = { f2bf(bv[0]), f2bf(bv[1]), f2bf(bv[2]), f2bf(bv[3]) };
            *(u16x4*)&Bs[row][c4] = bw;
        }
        __syncthreads();
#pragma unroll
        for (int ks = 0; ks < 2; ++ks) {
            int ko = (ks << 5) + ((lane >> 4) << 3);
            bf16x8 bfv[2];
#pragma unroll
            for (int n = 0; n < 2; ++n)
                bfv[n] = ldfrag(&Bs[(wn << 5) + (n << 4) + (lane & 15)][ko]);
#pragma unroll
            for (int mh = 0; mh < 2; ++mh) {
                bf16x8 af[4];
#pragma unroll
                for (int mi = 0; mi < 4; ++mi)
                    af[mi] = ldfrag(&As[(wm << 7) + (mh << 6) + (mi << 4) + (lane & 15)][ko]);
#pragma unroll
                for (int mi = 0; mi < 4; ++mi)
#pragma unroll
                    for (int n = 0; n < 2; ++n)
                        acc[(mh << 2) + mi][n] =
                            __builtin_amdgcn_mfma_f32_16x16x32_bf16(af[mi], bfv[n], acc[(mh << 2) + mi][n], 0, 0, 0);
            }
        }
        __syncthreads();
    }

    // epilogue: d = dhi + wm*8 + m (m=0..7), h = (lane>>4)*4 + r, t = tbase + wn*32 + n*16 + (lane&15)
    int cum = ws[16 + bs];
    int b = bs >> 2;
    int dhi = beta << 4;
    float* batch = out + 12288;

    f32x4 bias4[8];
#pragma unroll
    for (int m = 0; m < 8; ++m)
        bias4[m] = *(const f32x4*)(bias + (g << 8) + (wm << 7) + (m << 4) + ((lane >> 4) << 2));

    int d0 = dhi + (wm << 3);
    size_t hdbase = (size_t)((ls << 2) + b) << 4;    // (ls*4+b)*16

#pragma unroll
    for (int n = 0; n < 2; ++n) {
        int t = tbase + (wn << 5) + (n << 4) + (lane & 15);
        if (t >= len) continue;
        size_t tb = (size_t)(cum + t);
#pragma unroll
        for (int r = 0; r < 4; ++r) {
            int h = ((lane >> 4) << 2) + r;
            size_t off = (((hdbase + h) * Tmax + tb) << 6) + d0;
            f32x4 lo = { acc[0][n][r] + bias4[0][r], acc[1][n][r] + bias4[1][r],
                         acc[2][n][r] + bias4[2][r], acc[3][n][r] + bias4[3][r] };
            f32x4 hi = { acc[4][n][r] + bias4[4][r], acc[5][n][r] + bias4[5][r],
                         acc[6][n][r] + bias4[6][r], acc[7][n][r] + bias4[7][r] };
            *(f32x4*)(batch + off) = lo;
            *(f32x4*)(batch + off + 4) = hi;
        }
    }
}

extern "C" void kernel_launch(void* const* d_in, const int* in_sizes, int n_in,
                              void* d_out, int out_size, void* d_ws, size_t ws_size,
                              hipStream_t stream) {
    const float* lh   = (const float*)d_in[0];
    const int*   mask = (const int*)d_in[1];
    const float* wgt  = (const float*)d_in[2];
    const float* bias = (const float*)d_in[3];
    float* out = (float*)d_out;
    int* ws = (int*)d_ws;

    int Tmax = (out_size - 12288) / 131076;

    cums_kernel<<<1, 1024, 0, stream>>>(mask, ws, out + 12288 + (size_t)131072 * Tmax, Tmax);
    pooled_kernel<<<16 * 12, 256, 0, stream>>>(lh, mask, ws, out);

    int tailN = Tmax - 512; if (tailN < 1) tailN = 1;
    int nz = 4 * tailN * 8192;
    zerotail_kernel<<<(nz + 255) / 256, 256, 0, stream>>>(out + 12288, ws, Tmax, tailN);

    gemm_kernel<<<4096, 512, 0, stream>>>(lh, wgt, bias, ws, out, Tmax);
}